// Round 3
// baseline (280.774 us; speedup 1.0000x reference)
//
#include <hip/hip_runtime.h>

// Autoregressive LSTM log-prob, B=4096, L=256, H=32, D=2.
// Phase 1: lane = (batch, unit, gate-pair). 64 lanes per batch (1 wave = 1
// batch), lanes p=0 own gates {i,f}, p=1 own {g,o} for unit k = lane&31.
// 32 weights/lane held in registers (asm-pinned). Gate regroup + head
// reduction are pure in-wave shuffles; h broadcast via per-group LDS
// (in-wave, no barriers). 4096 waves = 4 waves/SIMD chip-wide.
// Phase 2: deferred ELU + log-softmax over the stored (S_sel, S_other)
// pairs, 0.5 * sum over t.

typedef float v2f __attribute__((ext_vector_type(2)));

#define LOG2E 1.4426950408889634f
#define LN2   0.6931471805599453f

__device__ __forceinline__ float fexp2(float x) { return __builtin_amdgcn_exp2f(x); }
__device__ __forceinline__ float flog2(float x) { return __builtin_amdgcn_logf(x); }
__device__ __forceinline__ float frcp(float x)  { return __builtin_amdgcn_rcpf(x); }

__device__ __forceinline__ float fsig(float x)   { return frcp(1.f + fexp2(-LOG2E * x)); }
__device__ __forceinline__ float ftanh_(float x) { return 1.f - 2.f * frcp(fexp2(2.f * LOG2E * x) + 1.f); }
__device__ __forceinline__ float felu(float x)   { return x > 0.f ? x : fexp2(LOG2E * x) - 1.f; }

constexpr int Bsz  = 4096;
constexpr int Lseq = 256;

template<bool DEFER>
__global__ __launch_bounds__(256, 4) void lstm_phase1(
    const int*   __restrict__ x,    // [B, L]
    const float* __restrict__ Wi,   // [2, 128]
    const float* __restrict__ Wh,   // [32, 128]
    const float* __restrict__ bh,   // [128]
    const float* __restrict__ Wo,   // [32, 2]
    const float* __restrict__ bo,   // [2]
    float2*      __restrict__ ws,   // [L, B] (S_sel+bo_sel, S_oth+bo_oth)
    float*       __restrict__ out)  // [B] (used only when !DEFER)
{
    const int tid  = threadIdx.x;
    const int lane = tid & 63;
    const int k    = lane & 31;       // hidden unit
    const int p    = lane >> 5;       // 0: gates {i,f}, 1: gates {g,o}
    const int g    = tid >> 6;        // local batch (wave index in block)
    const int b    = blockIdx.x * 4 + g;
    const int q0   = 2 * p;           // first gate column
    const int q1   = 2 * p + 1;       // second gate column

    // ---- per-lane weight columns (2 gates x 32 h-inputs), register-pinned
    v2f w0[16], w1[16];
#pragma unroll
    for (int j2 = 0; j2 < 16; ++j2) {
        w0[j2] = v2f{ Wh[(2 * j2) * 128 + q0 * 32 + k],
                      Wh[(2 * j2 + 1) * 128 + q0 * 32 + k] };
        w1[j2] = v2f{ Wh[(2 * j2) * 128 + q1 * 32 + k],
                      Wh[(2 * j2 + 1) * 128 + q1 * 32 + k] };
    }
#pragma unroll
    for (int j2 = 0; j2 < 16; ++j2) {
        asm volatile("" : "+v"(w0[j2]), "+v"(w1[j2]));   // forbid remat/spill-to-reload
    }

    const float bh0  = bh[q0 * 32 + k];
    const float bh1  = bh[q1 * 32 + k];
    const float bw00 = bh0 + Wi[q0 * 32 + k];          // spin = 0
    const float bw01 = bh1 + Wi[q1 * 32 + k];
    const float bw10 = bh0 + Wi[128 + q0 * 32 + k];    // spin = 1
    const float bw11 = bh1 + Wi[128 + q1 * 32 + k];
    const float wom  = Wo[k * 2 + p];                  // my half's output column
    const float bo0  = bo[0];
    const float bo1  = bo[1];

    __shared__ float hs[2][4][32];
    if (p == 0) hs[0][g][k] = 0.f;    // h_0 = 0; in-wave, no barrier needed

    const int bu = __builtin_amdgcn_readfirstlane(b);
    const int* __restrict__ xb = x + bu * Lseq;        // wave-uniform -> s_load

    float c = 0.f, lp = 0.f;
    float bc0 = bh0, bc1 = bh1;       // t=0 input is zeros (not one-hot)
    int s_cur = xb[0];

    for (int t = 0; t < Lseq; ++t) {
        const int s_next = xb[(t + 1) & (Lseq - 1)];   // uniform scalar prefetch

        // gates for my 2 columns: bias + h_{t-1} @ Wh[:, q]
        const float4* hv = reinterpret_cast<const float4*>(&hs[t & 1][g][0]);
        v2f a0 = v2f{ bc0, 0.f };
        v2f a1 = v2f{ bc1, 0.f };
#pragma unroll
        for (int j4 = 0; j4 < 8; ++j4) {
            const float4 h4 = hv[j4];                  // broadcast read (1 addr/wave)
            const v2f lo = v2f{ h4.x, h4.y };
            const v2f hi = v2f{ h4.z, h4.w };
            a0 = __builtin_elementwise_fma(lo, w0[2 * j4],     a0);
            a0 = __builtin_elementwise_fma(hi, w0[2 * j4 + 1], a0);
            a1 = __builtin_elementwise_fma(lo, w1[2 * j4],     a1);
            a1 = __builtin_elementwise_fma(hi, w1[2 * j4 + 1], a1);
        }
        const float ga = a0.x + a0.y;
        const float gb = a1.x + a1.y;

        // nonlinearity: p=0 -> sig(i), sig(f) ; p=1 -> tanh(g), sig(o)
        const float n0 = p ? ftanh_(ga) : fsig(ga);
        const float n1 = fsig(gb);
        const float m0 = __shfl_xor(n0, 32, 64);
        const float m1 = __shfl_xor(n1, 32, 64);
        const float gi = p ? m0 : n0;
        const float gf = p ? m1 : n1;
        const float gg = p ? n0 : m0;
        const float go = p ? n1 : m1;

        c = gf * c + gi * gg;
        const float h = go * ftanh_(c);
        if (p == 0) hs[(t + 1) & 1][g][k] = h;         // in-wave, in-order DS pipe

        // head: S_p = sum_k h[k] * Wo[k][p], butterfly within each 32-half
        float ss = h * wom;
        ss += __shfl_xor(ss, 1, 64);
        ss += __shfl_xor(ss, 2, 64);
        ss += __shfl_xor(ss, 4, 64);
        ss += __shfl_xor(ss, 8, 64);
        ss += __shfl_xor(ss, 16, 64);
        const float so = __shfl_xor(ss, 32, 64);       // other half's sum
        const float S0 = p ? so : ss;
        const float S1 = p ? ss : so;

        if (DEFER) {
            if (lane == 0) {
                const float av = s_cur ? S1 + bo1 : S0 + bo0;   // selected logit (pre-ELU)
                const float bv = s_cur ? S0 + bo0 : S1 + bo1;   // other logit
                ws[t * Bsz + b] = make_float2(av, bv);
            }
        } else {
            const float o0 = felu(S0 + bo0);
            const float o1 = felu(S1 + bo1);
            const float mx = fmaxf(o0, o1);
            const float mn = fminf(o0, o1);
            lp += (s_cur ? o1 : o0)
                - (mx + LN2 * flog2(1.f + fexp2(LOG2E * (mn - mx))));
        }

        bc0 = s_cur ? bw10 : bw00;
        bc1 = s_cur ? bw11 : bw01;
        s_cur = s_next;
    }

    if (!DEFER) {
        if (lane == 0) out[b] = 0.5f * lp;
    }
}

__global__ __launch_bounds__(256) void lstm_phase2(
    const float2* __restrict__ ws,   // [L, B] (sel, other) pre-ELU logits
    float*        __restrict__ out)  // [B]
{
    const int tid   = threadIdx.x;
    const int bl    = tid & 63;
    const int chunk = tid >> 6;      // 4 time-chunks of 64 steps
    const int b     = blockIdx.x * 64 + bl;

    float lp = 0.f;
    for (int tt = 0; tt < 64; ++tt) {
        const int t = chunk * 64 + tt;
        const float2 sv = ws[t * Bsz + b];             // coalesced over b
        const float oa = felu(sv.x);
        const float ob = felu(sv.y);
        const float mx = fmaxf(oa, ob);
        const float mn = fminf(oa, ob);
        lp += oa - (mx + LN2 * flog2(1.f + fexp2(LOG2E * (mn - mx))));
    }

    __shared__ float red[4][64];
    red[chunk][bl] = lp;
    __syncthreads();
    if (chunk == 0) {
        out[b] = 0.5f * (red[0][bl] + red[1][bl] + red[2][bl] + red[3][bl]);
    }
}

extern "C" void kernel_launch(void* const* d_in, const int* in_sizes, int n_in,
                              void* d_out, int out_size, void* d_ws, size_t ws_size,
                              hipStream_t stream) {
    const int*   x  = (const int*)d_in[0];
    const float* Wi = (const float*)d_in[1];
    const float* Wh = (const float*)d_in[2];
    const float* bh = (const float*)d_in[3];
    const float* Wo = (const float*)d_in[4];
    const float* bo = (const float*)d_in[5];
    float* out = (float*)d_out;

    const size_t need = (size_t)Bsz * Lseq * sizeof(float2);
    const bool defer = ws_size >= need;

    dim3 grid(Bsz / 4);   // 1024 blocks, 4 batches (waves) each
    dim3 block(256);
    if (defer) {
        lstm_phase1<true><<<grid, block, 0, stream>>>(x, Wi, Wh, bh, Wo, bo,
                                                      (float2*)d_ws, out);
        lstm_phase2<<<dim3(Bsz / 64), block, 0, stream>>>((const float2*)d_ws, out);
    } else {
        lstm_phase1<false><<<grid, block, 0, stream>>>(x, Wi, Wh, bh, Wo, bo,
                                                       nullptr, out);
    }
}

// Round 4
// 228.290 us; speedup vs baseline: 1.2299x; 1.2299x over previous
//
#include <hip/hip_runtime.h>

// Autoregressive LSTM log-prob via MFMA, B=4096, L=256, H=32, D=2.
// 256 workgroups x 128 threads (2 waves). Each WG owns 16 batches for the
// full 256-step recurrence. Per step: gates [16,128] = h[16,32] @ Wh'[32,128]
// as 4x mfma_f32_16x16x32_bf16 per wave (wave uh owns unit half uh), plus one
// head MFMA (Wo padded to 16 cols) for the logits of the PREVIOUS step.
// Gate scales folded into weights/biases: i,f,o cols x(-log2e), g cols
// x(+2log2e) so sigmoid = rcp(1+exp2(a~)), tanh = 1-2*rcp(1+exp2(a~)).
// Bias + Wi[spin] enters as the MFMA C operand. h transposes D-layout ->
// A-layout through a double-buffered LDS region; one barrier per step.

typedef __attribute__((ext_vector_type(8))) short bf16x8;
typedef __attribute__((ext_vector_type(4))) float f32x4;

#define LOG2E 1.4426950408889634f
#define LN2   0.6931471805599453f

__device__ __forceinline__ float fexp2(float x) { return __builtin_amdgcn_exp2f(x); }
__device__ __forceinline__ float flog2(float x) { return __builtin_amdgcn_logf(x); }
__device__ __forceinline__ float frcp(float x)  { return __builtin_amdgcn_rcpf(x); }

__device__ __forceinline__ unsigned short f2bf(float f) {   // RNE f32->bf16
    unsigned u = __builtin_bit_cast(unsigned, f);
    u = (u + 0x7FFFu + ((u >> 16) & 1u)) >> 16;
    return (unsigned short)u;
}

constexpr int Bsz = 4096;

__global__ __launch_bounds__(128) void lstm_mfma(
    const int*   __restrict__ x,    // [B, 256]
    const float* __restrict__ Wi,   // [2, 128]
    const float* __restrict__ Wh,   // [32, 128]
    const float* __restrict__ bh,   // [128]
    const float* __restrict__ Wo,   // [32, 2]
    const float* __restrict__ bo,   // [2]
    float*       __restrict__ out)  // [B]
{
    const int tid  = threadIdx.x;
    const int lane = tid & 63;
    const int uh   = tid >> 6;        // wave id = unit half (0/1)
    const int col  = lane & 15;       // D col / A row / B col
    const int oct  = lane >> 4;       // k-octet & D row-quad selector
    const int b0   = blockIdx.x * 16;

    __shared__ int spinbuf[16][256];                          // 16 KB: x slice
    __shared__ __align__(16) unsigned short abuf[2][16][40];  // A-frag dbuf, 80 B rows

    // ---- stage this WG's x rows into LDS (coalesced int4) ----
    {
        const int bl = tid >> 3, ch = tid & 7;
        const int4* src = reinterpret_cast<const int4*>(x + (b0 + bl) * 256 + ch * 32);
        int4* dst = reinterpret_cast<int4*>(&spinbuf[bl][ch * 32]);
#pragma unroll
        for (int i = 0; i < 8; ++i) dst[i] = src[i];
    }

    // ---- B fragments (once). k-permutation sigma: k = 2*(u&15) + (u>>4),
    // i.e. u = (k>>1) + ((k&1)<<4); A uses the same permutation on write.
    const float gscale[4] = { -LOG2E, -LOG2E, 2.f * LOG2E, -LOG2E };
    bf16x8 bfrag[4];
#pragma unroll
    for (int q = 0; q < 4; ++q) {
        const int n = q * 32 + uh * 16 + col;
#pragma unroll
        for (int j = 0; j < 8; ++j) {
            const int k = oct * 8 + j;
            const int u = (k >> 1) + ((k & 1) << 4);
            bfrag[q][j] = (short)f2bf(gscale[q] * Wh[u * 128 + n]);
        }
    }
    bf16x8 wofrag;   // head B-frag: Wo padded to 16 cols, UNSCALED
#pragma unroll
    for (int j = 0; j < 8; ++j) {
        const int k = oct * 8 + j;
        const int u = (k >> 1) + ((k & 1) << 4);
        wofrag[j] = (col < 2) ? (short)f2bf(Wo[u * 2 + col]) : (short)0;
    }
    float bw0[4], bw1[4], bz[4];
#pragma unroll
    for (int q = 0; q < 4; ++q) {
        const int n = q * 32 + uh * 16 + col;
        bz[q]  = gscale[q] * bh[n];
        bw0[q] = gscale[q] * (bh[n] + Wi[n]);
        bw1[q] = gscale[q] * (bh[n] + Wi[128 + n]);
    }
    const float bo0 = bo[0], bo1 = bo[1];

    __syncthreads();   // spin staging visible to both waves

    // ---- peel t=0: input zeros, h=0 -> gates = scaled bh, identical per batch
    float c[4];
    float lp0 = 0.f, lp1 = 0.f;
    {
        const float gi = frcp(1.f + fexp2(bz[0]));
        const float tg = 1.f - 2.f * frcp(1.f + fexp2(bz[2]));
        const float go = frcp(1.f + fexp2(bz[3]));
        const float cc = gi * tg;                       // c0 = 0
        const float tc = 1.f - 2.f * frcp(1.f + fexp2(2.f * LOG2E * cc));
        const unsigned short hb = f2bf(go * tc);
#pragma unroll
        for (int r = 0; r < 4; ++r) {
            c[r] = cc;
            abuf[0][oct * 4 + r][2 * col + uh] = hb;    // A[m][sigma(u)]
        }
    }
    __syncthreads();

    const f32x4 zero4 = { 0.f, 0.f, 0.f, 0.f };

    for (int t = 1; t < 256; ++t) {
        // spins at step t-1 (drives Wi select AND step-(t-1) logp select)
        int sp[4];
#pragma unroll
        for (int r = 0; r < 4; ++r) sp[r] = spinbuf[oct * 4 + r][t - 1];

        // A fragment = h_{t-1} (written last iter / peel)
        const bf16x8 afrag =
            *reinterpret_cast<const bf16x8*>(&abuf[(t + 1) & 1][col][oct * 8]);

        // gate MFMAs, C = scaled (bh + Wi[spin])
        f32x4 acc[4];
#pragma unroll
        for (int q = 0; q < 4; ++q) {
            f32x4 ci;
#pragma unroll
            for (int r = 0; r < 4; ++r) ci[r] = sp[r] ? bw1[q] : bw0[q];
            acc[q] = __builtin_amdgcn_mfma_f32_16x16x32_bf16(afrag, bfrag[q], ci, 0, 0, 0);
        }
        // head MFMA: logits of step t-1
        const f32x4 hacc =
            __builtin_amdgcn_mfma_f32_16x16x32_bf16(afrag, wofrag, zero4, 0, 0, 0);

        // nonlinearity + cell update (per lane: 4 batches x 1 unit-col)
#pragma unroll
        for (int r = 0; r < 4; ++r) {
            const float gi = frcp(1.f + fexp2(acc[0][r]));
            const float gf = frcp(1.f + fexp2(acc[1][r]));
            const float tg = 1.f - 2.f * frcp(1.f + fexp2(acc[2][r]));
            const float go = frcp(1.f + fexp2(acc[3][r]));
            c[r] = gf * c[r] + gi * tg;
            const float tc = 1.f - 2.f * frcp(1.f + fexp2(2.f * LOG2E * c[r]));
            abuf[t & 1][oct * 4 + r][2 * col + uh] = f2bf(go * tc);
        }

        // logp for step t-1; wave uh handles regs {2uh, 2uh+1}
#pragma unroll
        for (int rr = 0; rr < 2; ++rr) {
            const int r = 2 * uh + rr;
            const float mine  = hacc[r];
            const float other = __shfl_xor(mine, 1, 64);
            const float S0 = mine + bo0;                // valid on col==0 lanes
            const float S1 = other + bo1;
            const float o0 = S0 > 0.f ? S0 : fexp2(LOG2E * S0) - 1.f;
            const float o1 = S1 > 0.f ? S1 : fexp2(LOG2E * S1) - 1.f;
            const float mx = fmaxf(o0, o1), mn = fminf(o0, o1);
            const float lse = mx + LN2 * flog2(1.f + fexp2(LOG2E * (mn - mx)));
            const float sel = sp[r] ? o1 : o0;
            if (rr == 0) lp0 += sel - lse; else lp1 += sel - lse;
        }

        __syncthreads();   // h_t visible before iter t+1 reads it
    }

    // ---- tail: logp for step 255 (h_255 is in buf[1]) ----
    {
        int sp[4];
#pragma unroll
        for (int r = 0; r < 4; ++r) sp[r] = spinbuf[oct * 4 + r][255];
        const bf16x8 afrag =
            *reinterpret_cast<const bf16x8*>(&abuf[1][col][oct * 8]);
        const f32x4 hacc =
            __builtin_amdgcn_mfma_f32_16x16x32_bf16(afrag, wofrag, zero4, 0, 0, 0);
#pragma unroll
        for (int rr = 0; rr < 2; ++rr) {
            const int r = 2 * uh + rr;
            const float mine  = hacc[r];
            const float other = __shfl_xor(mine, 1, 64);
            const float S0 = mine + bo0;
            const float S1 = other + bo1;
            const float o0 = S0 > 0.f ? S0 : fexp2(LOG2E * S0) - 1.f;
            const float o1 = S1 > 0.f ? S1 : fexp2(LOG2E * S1) - 1.f;
            const float mx = fmaxf(o0, o1), mn = fminf(o0, o1);
            const float lse = mx + LN2 * flog2(1.f + fexp2(LOG2E * (mn - mx)));
            const float sel = sp[r] ? o1 : o0;
            if (rr == 0) lp0 += sel - lse; else lp1 += sel - lse;
        }
    }

    if (col == 0) {
        out[b0 + oct * 4 + 2 * uh + 0] = 0.5f * lp0;
        out[b0 + oct * 4 + 2 * uh + 1] = 0.5f * lp1;
    }
}

extern "C" void kernel_launch(void* const* d_in, const int* in_sizes, int n_in,
                              void* d_out, int out_size, void* d_ws, size_t ws_size,
                              hipStream_t stream) {
    const int*   x  = (const int*)d_in[0];
    const float* Wi = (const float*)d_in[1];
    const float* Wh = (const float*)d_in[2];
    const float* bh = (const float*)d_in[3];
    const float* Wo = (const float*)d_in[4];
    const float* bo = (const float*)d_in[5];
    float* out = (float*)d_out;

    lstm_mfma<<<dim3(Bsz / 16), dim3(128), 0, stream>>>(x, Wi, Wh, bh, Wo, bo, out);
}

// Round 5
// 228.127 us; speedup vs baseline: 1.2308x; 1.0007x over previous
//
#include <hip/hip_runtime.h>

// Autoregressive LSTM log-prob via lane-local MFMA recurrence.
// B=4096, L=256, H=32, D=2. 256 WGs x 64 threads (ONE wave each, 16 batches).
// Orientation: gates^T = Wh^T @ h^T  (A = weights, B = h, batch = lane&15).
// K-permutation sigma(u) = 8*((u&15)>>2) + (u&3) + 4*(u>>4) makes the D-tile
// cell outputs of each lane exactly its own B-fragment k-slots for the next
// step: the whole recurrence is lane-local -- no LDS / shuffles / barriers.
// Gate scales folded into weights & biases (i,f,o: -log2e; g: +2log2e).
// Head MFMA (Wo^T as A) yields S0,S1 on oct0 lanes; S pairs buffered in LDS,
// ELU + log-softmax + time-reduction done post-loop. Spins: padded byte LDS,
// conflict-free broadcast, prefetched one step ahead.

typedef __attribute__((ext_vector_type(8))) short bf16x8;
typedef __attribute__((ext_vector_type(4))) float f32x4;

#define LOG2E 1.4426950408889634f
#define LN2   0.6931471805599453f

__device__ __forceinline__ float fexp2(float x) { return __builtin_amdgcn_exp2f(x); }
__device__ __forceinline__ float flog2(float x) { return __builtin_amdgcn_logf(x); }
__device__ __forceinline__ float frcp(float x)  { return __builtin_amdgcn_rcpf(x); }

__device__ __forceinline__ float fsig(float x)   { return frcp(1.f + fexp2(-LOG2E * x)); }
__device__ __forceinline__ float ftanh_(float x) { return 1.f - 2.f * frcp(fexp2(2.f * LOG2E * x) + 1.f); }
__device__ __forceinline__ float felu(float x)   { return x > 0.f ? x : fexp2(LOG2E * x) - 1.f; }

__device__ __forceinline__ unsigned short f2bf(float f) {   // RNE f32->bf16
    unsigned u = __builtin_bit_cast(unsigned, f);
    u = (u + 0x7FFFu + ((u >> 16) & 1u)) >> 16;
    return (unsigned short)u;
}

constexpr int Bsz = 4096;

__global__ __launch_bounds__(64, 1) void lstm_mfma1w(
    const int*   __restrict__ x,    // [B, 256]
    const float* __restrict__ Wi,   // [2, 128]
    const float* __restrict__ Wh,   // [32, 128]
    const float* __restrict__ bh,   // [128]
    const float* __restrict__ Wo,   // [32, 2]
    const float* __restrict__ bo,   // [2]
    float*       __restrict__ out)  // [B]
{
    const int lane = threadIdx.x & 63;
    const int m    = lane & 15;     // batch column (n in B, col in D)
    const int oct  = lane >> 4;
    const int b0   = blockIdx.x * 16;

    __shared__ char   spinT[16][260];     // [batch][t] bytes, pad->conflict-free
    __shared__ float2 Sbuf[256][16];      // raw logits (S0,S1) per (t, batch)

    // ---- stage spins: lane -> (batch lane>>2, 64 t's), packed int4 reads ----
    {
        const int bl = lane >> 2;
        const int t0 = (lane & 3) * 64;
        const int4* src = reinterpret_cast<const int4*>(x + (b0 + bl) * 256 + t0);
#pragma unroll
        for (int i = 0; i < 16; ++i) {
            const int4 v = src[i];
            const int packed = (v.x & 1) | ((v.y & 1) << 8) |
                               ((v.z & 1) << 16) | ((v.w & 1) << 24);
            *reinterpret_cast<int*>(&spinT[bl][t0 + 4 * i]) = packed;
        }
    }

    // ---- weight A-fragments. Tile t covers gate-cols 32*(t>>1)+16*(t&1)+m,
    // gate q = t>>1 (order i,f,g,o). k-slot j -> unit sigma^{-1}(oct*8+j).
    bf16x8 wfrag[8];
#pragma unroll
    for (int tt = 0; tt < 8; ++tt) {
        const int q = tt >> 1;
        const float gs = (q == 2) ? 2.f * LOG2E : -LOG2E;
        const int colg = 32 * q + 16 * (tt & 1) + m;
#pragma unroll
        for (int j = 0; j < 8; ++j) {
            const int u = 4 * oct + (j & 3) + 16 * (j >> 2);
            wfrag[tt][j] = (short)f2bf(gs * Wh[u * 128 + colg]);
        }
    }
    bf16x8 wofragA;   // head: Wo^T padded to 16 rows, unscaled
#pragma unroll
    for (int j = 0; j < 8; ++j) {
        const int u = 4 * oct + (j & 3) + 16 * (j >> 2);
        wofragA[j] = (m < 2) ? (short)f2bf(Wo[u * 2 + m]) : (short)0;
    }

    // ---- per-lane scaled biases: rows oct*4+r of each tile ----
    f32x4 cb0[8], cdw[8];
#pragma unroll
    for (int tt = 0; tt < 8; ++tt) {
        const int q = tt >> 1;
        const float gs = (q == 2) ? 2.f * LOG2E : -LOG2E;
#pragma unroll
        for (int r = 0; r < 4; ++r) {
            const int colg = 32 * q + 16 * (tt & 1) + 4 * oct + r;
            const float v0 = gs * (bh[colg] + Wi[colg]);
            const float v1 = gs * (bh[colg] + Wi[128 + colg]);
            cb0[tt][r] = v0;
            cdw[tt][r] = v1 - v0;
        }
    }

    // ---- peel t=0: input zeros, h=c=0 -> gates = bh (identical per batch)
    float c_lo[4], c_hi[4];
    bf16x8 hfrag;
#pragma unroll
    for (int r = 0; r < 4; ++r) {
        const int ul = 4 * oct + r, uh2 = ul + 16;
        c_lo[r] = fsig(bh[ul])  * ftanh_(bh[64 + ul]);
        c_hi[r] = fsig(bh[uh2]) * ftanh_(bh[64 + uh2]);
        hfrag[r]     = (short)f2bf(fsig(bh[96 + ul])  * ftanh_(c_lo[r]));
        hfrag[4 + r] = (short)f2bf(fsig(bh[96 + uh2]) * ftanh_(c_hi[r]));
    }

    const f32x4 zero4 = { 0.f, 0.f, 0.f, 0.f };
    float spf = (float)spinT[m][0];   // x[0], consumed by iteration t=1

    for (int t = 1; t < 256; ++t) {
        // C operands: scaled (bh + Wi[spin(t-1)]) for this lane's rows
        f32x4 cc[8];
#pragma unroll
        for (int tt = 0; tt < 8; ++tt)
#pragma unroll
            for (int r = 0; r < 4; ++r)
                cc[tt][r] = fmaf(spf, cdw[tt][r], cb0[tt][r]);

        f32x4 acc[8];
#pragma unroll
        for (int tt = 0; tt < 8; ++tt)
            acc[tt] = __builtin_amdgcn_mfma_f32_16x16x32_bf16(wfrag[tt], hfrag, cc[tt], 0, 0, 0);
        const f32x4 hacc =
            __builtin_amdgcn_mfma_f32_16x16x32_bf16(wofragA, hfrag, zero4, 0, 0, 0);

        // prefetch next spin (off critical path)
        const float spn = (float)spinT[m][t];

        // buffer step t-1 logits (oct0 lanes own rows 0,1 = S0,S1)
        if (oct == 0) Sbuf[t - 1][m] = make_float2(hacc[0], hacc[1]);

        // cells: lane-local. lo cells use even tiles, hi cells odd tiles.
        // e_i=e^{-i}, e_f=e^{-f}, e_g=e^{2g}, e_o=e^{-o} (scales pre-folded).
#pragma unroll
        for (int r = 0; r < 4; ++r) {
            {   // lo cell (unit 4*oct+r)
                const float ei = fexp2(acc[0][r]), ef = fexp2(acc[2][r]);
                const float eg = fexp2(acc[4][r]), eo = fexp2(acc[6][r]);
                const float gf = frcp(1.f + ef);
                const float igt = (eg - 1.f) * frcp((1.f + ei) * (1.f + eg));
                c_lo[r] = fmaf(gf, c_lo[r], igt);
                const float ec = fexp2(2.f * LOG2E * c_lo[r]);
                const float h  = (ec - 1.f) * frcp((1.f + eo) * (1.f + ec));
                hfrag[r] = (short)f2bf(h);
            }
            {   // hi cell (unit 16+4*oct+r)
                const float ei = fexp2(acc[1][r]), ef = fexp2(acc[3][r]);
                const float eg = fexp2(acc[5][r]), eo = fexp2(acc[7][r]);
                const float gf = frcp(1.f + ef);
                const float igt = (eg - 1.f) * frcp((1.f + ei) * (1.f + eg));
                c_hi[r] = fmaf(gf, c_hi[r], igt);
                const float ec = fexp2(2.f * LOG2E * c_hi[r]);
                const float h  = (ec - 1.f) * frcp((1.f + eo) * (1.f + ec));
                hfrag[4 + r] = (short)f2bf(h);
            }
        }
        spf = spn;
    }

    // tail: logits of step 255
    {
        const f32x4 hacc =
            __builtin_amdgcn_mfma_f32_16x16x32_bf16(wofragA, hfrag, zero4, 0, 0, 0);
        if (oct == 0) Sbuf[255][m] = make_float2(hacc[0], hacc[1]);
    }

    // ---- post phase: ELU + log-softmax + sum over t (same wave, no barrier:
    // all Sbuf/spinT traffic is in-wave, DS pipe is in-order) ----
    const float bo0 = bo[0], bo1 = bo[1];
    float lp = 0.f;
    const int tq = lane >> 4;   // 4 time-quarters
#pragma unroll 4
    for (int i = 0; i < 64; ++i) {
        const int t = tq * 64 + i;
        const float2 sv = Sbuf[t][m];
        const int sp = spinT[m][t];
        const float o0 = felu(sv.x + bo0);
        const float o1 = felu(sv.y + bo1);
        const float mx = fmaxf(o0, o1), mn = fminf(o0, o1);
        const float lse = mx + LN2 * flog2(1.f + fexp2(LOG2E * (mn - mx)));
        lp += (sp ? o1 : o0) - lse;
    }
    lp += __shfl_xor(lp, 16, 64);
    lp += __shfl_xor(lp, 32, 64);
    if (tq == 0) out[b0 + m] = 0.5f * lp;
}

extern "C" void kernel_launch(void* const* d_in, const int* in_sizes, int n_in,
                              void* d_out, int out_size, void* d_ws, size_t ws_size,
                              hipStream_t stream) {
    const int*   x  = (const int*)d_in[0];
    const float* Wi = (const float*)d_in[1];
    const float* Wh = (const float*)d_in[2];
    const float* bh = (const float*)d_in[3];
    const float* Wo = (const float*)d_in[4];
    const float* bo = (const float*)d_in[5];
    float* out = (float*)d_out;

    lstm_mfma1w<<<dim3(Bsz / 16), dim3(64), 0, stream>>>(x, Wi, Wh, bh, Wo, bo, out);
}

// Round 6
// 165.778 us; speedup vs baseline: 1.6937x; 1.3761x over previous
//
#include <hip/hip_runtime.h>

// Autoregressive LSTM log-prob via MFMA, 4-wave split-cell design.
// B=4096, L=256, H=32, D=2. 256 WGs x 256 threads (4 waves), 16 batches/WG.
// Orientation: gates^T = Wh^T @ h^T (A = weights, B = h, batch = lane&15).
// All 4 waves redundantly run the 8 gate MFMAs (MFMA pipe is nearly idle);
// wave w cell-updates only units {4*oct+w, 16+4*oct+w} -> per-wave
// transcendental work drops 4x vs the 1-wave design. Wave w's A-fragments
// are row-rotated by w so its cells sit in element 0 of every accumulator.
// h exchange: double-buffered LDS tile, 2 b16 writes + 1 ds_read_b128 per
// lane, ONE barrier per step. Gate scales folded into weights/biases
// (i,f,o: -log2e; g: +2log2e). Logits buffered; ELU/log-softmax post-loop.

typedef __attribute__((ext_vector_type(8))) short bf16x8;
typedef __attribute__((ext_vector_type(4))) float f32x4;

#define LOG2E 1.4426950408889634f
#define LN2   0.6931471805599453f

__device__ __forceinline__ float fexp2(float x) { return __builtin_amdgcn_exp2f(x); }
__device__ __forceinline__ float flog2(float x) { return __builtin_amdgcn_logf(x); }
__device__ __forceinline__ float frcp(float x)  { return __builtin_amdgcn_rcpf(x); }

__device__ __forceinline__ float fsig(float x)   { return frcp(1.f + fexp2(-LOG2E * x)); }
__device__ __forceinline__ float ftanh_(float x) { return 1.f - 2.f * frcp(fexp2(2.f * LOG2E * x) + 1.f); }
__device__ __forceinline__ float felu(float x)   { return x > 0.f ? x : fexp2(LOG2E * x) - 1.f; }

__device__ __forceinline__ unsigned short f2bf(float f) {   // RNE f32->bf16
    unsigned u = __builtin_bit_cast(unsigned, f);
    u = (u + 0x7FFFu + ((u >> 16) & 1u)) >> 16;
    return (unsigned short)u;
}

constexpr int Bsz = 4096;

__global__ __launch_bounds__(256, 1) void lstm_mfma4w(
    const int*   __restrict__ x,    // [B, 256]
    const float* __restrict__ Wi,   // [2, 128]
    const float* __restrict__ Wh,   // [32, 128]
    const float* __restrict__ bh,   // [128]
    const float* __restrict__ Wo,   // [32, 2]
    const float* __restrict__ bo,   // [2]
    float*       __restrict__ out)  // [B]
{
    const int tid  = threadIdx.x;
    const int w    = tid >> 6;      // wave id 0..3 (owns gate-row r = w)
    const int lane = tid & 63;
    const int m    = lane & 15;     // batch (B col / D col / A row index)
    const int oct  = lane >> 4;
    const int b0   = blockIdx.x * 16;

    __shared__ char   spinT[16][260];      // [batch][t], padded row
    __shared__ float2 Sbuf[256][16];       // raw logits (S0,S1) per (t,batch)
    __shared__ short  hbuf[2][16][32];     // h dbuf: [batch][k-slot] bf16
    __shared__ float  red[4][16];

    // ---- stage spins (256 threads, 16 t's each) ----
    {
        const int bl = tid >> 4;
        const int t0 = (tid & 15) * 16;
        const int4* src = reinterpret_cast<const int4*>(x + (b0 + bl) * 256 + t0);
#pragma unroll
        for (int i = 0; i < 4; ++i) {
            const int4 v = src[i];
            const int packed = (v.x & 1) | ((v.y & 1) << 8) |
                               ((v.z & 1) << 16) | ((v.w & 1) << 24);
            *reinterpret_cast<int*>(&spinT[bl][t0 + 4 * i]) = packed;
        }
    }

    // ---- weight A-frags, rows rotated by w: element 0 of D = this wave's unit.
    // k-slot j of oct -> unit u = 4*oct + (j&3) + 16*(j>>2).
    bf16x8 wfrag[8];
#pragma unroll
    for (int tt = 0; tt < 8; ++tt) {
        const int q = tt >> 1;
        const float gs = (q == 2) ? 2.f * LOG2E : -LOG2E;
        const int colg = 32 * q + 16 * (tt & 1) + ((m + w) & 15);
#pragma unroll
        for (int j = 0; j < 8; ++j) {
            const int u = 4 * oct + (j & 3) + 16 * (j >> 2);
            wfrag[tt][j] = (short)f2bf(gs * Wh[u * 128 + colg]);
        }
    }
    bf16x8 wofragA;   // head: Wo^T padded to 16 rows, unscaled (wave 0 uses it)
#pragma unroll
    for (int j = 0; j < 8; ++j) {
        const int u = 4 * oct + (j & 3) + 16 * (j >> 2);
        wofragA[j] = (m < 2) ? (short)f2bf(Wo[u * 2 + m]) : (short)0;
    }

    // ---- per-lane scaled biases for its 8 gate values (r = w rows) ----
    float bv0[8], bvd[8];
#pragma unroll
    for (int tt = 0; tt < 8; ++tt) {
        const int q = tt >> 1;
        const float gs = (q == 2) ? 2.f * LOG2E : -LOG2E;
        const int colg = 32 * q + 16 * (tt & 1) + 4 * oct + w;
        const float v0 = gs * (bh[colg] + Wi[colg]);
        const float v1 = gs * (bh[colg] + Wi[128 + colg]);
        bv0[tt] = v0;
        bvd[tt] = v1 - v0;
    }

    // ---- peel t=0: input zeros, h=c=0 -> gates = bh ----
    float c_lo, c_hi;
    {
        const int ul = 4 * oct + w, uh2 = ul + 16;
        c_lo = fsig(bh[ul])  * ftanh_(bh[64 + ul]);
        c_hi = fsig(bh[uh2]) * ftanh_(bh[64 + uh2]);
        hbuf[0][m][8 * oct + w]     = (short)f2bf(fsig(bh[96 + ul])  * ftanh_(c_lo));
        hbuf[0][m][8 * oct + 4 + w] = (short)f2bf(fsig(bh[96 + uh2]) * ftanh_(c_hi));
    }
    __syncthreads();

    const f32x4 zero4 = { 0.f, 0.f, 0.f, 0.f };
    float spf = (float)spinT[m][0];   // x[0], consumed by iteration t=1

    for (int t = 1; t < 256; ++t) {
        const bf16x8 hfrag = *reinterpret_cast<const bf16x8*>(&hbuf[(t + 1) & 1][m][oct * 8]);

        f32x4 acc[8];
#pragma unroll
        for (int tt = 0; tt < 8; ++tt)
            acc[tt] = __builtin_amdgcn_mfma_f32_16x16x32_bf16(wfrag[tt], hfrag, zero4, 0, 0, 0);

        if (w == 0) {   // head: logits of step t-1 (wave-uniform branch)
            const f32x4 hacc =
                __builtin_amdgcn_mfma_f32_16x16x32_bf16(wofragA, hfrag, zero4, 0, 0, 0);
            if (oct == 0) Sbuf[t - 1][m] = make_float2(hacc[0], hacc[1]);
        }

        const float spn = (float)spinT[m][t];   // prefetch next spin

        // gates for this wave's 2 cells (element 0 after row-rotation)
        float g[8];
#pragma unroll
        for (int tt = 0; tt < 8; ++tt)
            g[tt] = acc[tt][0] + fmaf(spf, bvd[tt], bv0[tt]);

        // lo cell (unit 4*oct+w): tt even; hi cell (16+4*oct+w): tt odd.
        // e_i=e^{-i}, e_f=e^{-f}, e_g=e^{2g}, e_o=e^{-o} (scales pre-folded).
        {
            const float ei = fexp2(g[0]), ef = fexp2(g[2]);
            const float eg = fexp2(g[4]), eo = fexp2(g[6]);
            const float gf = frcp(1.f + ef);
            const float igt = (eg - 1.f) * frcp((1.f + ei) * (1.f + eg));
            c_lo = fmaf(gf, c_lo, igt);
            const float ec = fexp2(2.f * LOG2E * c_lo);
            const float h  = (ec - 1.f) * frcp((1.f + eo) * (1.f + ec));
            hbuf[t & 1][m][8 * oct + w] = (short)f2bf(h);
        }
        {
            const float ei = fexp2(g[1]), ef = fexp2(g[3]);
            const float eg = fexp2(g[5]), eo = fexp2(g[7]);
            const float gf = frcp(1.f + ef);
            const float igt = (eg - 1.f) * frcp((1.f + ei) * (1.f + eg));
            c_hi = fmaf(gf, c_hi, igt);
            const float ec = fexp2(2.f * LOG2E * c_hi);
            const float h  = (ec - 1.f) * frcp((1.f + eo) * (1.f + ec));
            hbuf[t & 1][m][8 * oct + 4 + w] = (short)f2bf(h);
        }

        spf = spn;
        __syncthreads();   // h_t visible to all waves
    }

    // ---- tail: logits of step 255 (h_255 in hbuf[1]) ----
    if (w == 0) {
        const bf16x8 hfrag = *reinterpret_cast<const bf16x8*>(&hbuf[1][m][oct * 8]);
        const f32x4 hacc =
            __builtin_amdgcn_mfma_f32_16x16x32_bf16(wofragA, hfrag, zero4, 0, 0, 0);
        if (oct == 0) Sbuf[255][m] = make_float2(hacc[0], hacc[1]);
    }
    __syncthreads();

    // ---- post phase: ELU + log-softmax + sum over t, split 16 ways ----
    const float bo0 = bo[0], bo1 = bo[1];
    float lp = 0.f;
#pragma unroll 4
    for (int i = 0; i < 16; ++i) {
        const int t = 64 * w + 16 * oct + i;
        const float2 sv = Sbuf[t][m];
        const int sp = spinT[m][t];
        const float o0 = felu(sv.x + bo0);
        const float o1 = felu(sv.y + bo1);
        const float mx = fmaxf(o0, o1), mn = fminf(o0, o1);
        const float lse = mx + LN2 * flog2(1.f + fexp2(LOG2E * (mn - mx)));
        lp += (sp ? o1 : o0) - lse;
    }
    lp += __shfl_xor(lp, 16, 64);   // reduce over oct
    lp += __shfl_xor(lp, 32, 64);
    if (lane < 16) red[w][lane] = lp;
    __syncthreads();
    if (tid < 16)
        out[b0 + tid] = 0.5f * (red[0][tid] + red[1][tid] + red[2][tid] + red[3][tid]);
}

extern "C" void kernel_launch(void* const* d_in, const int* in_sizes, int n_in,
                              void* d_out, int out_size, void* d_ws, size_t ws_size,
                              hipStream_t stream) {
    const int*   x  = (const int*)d_in[0];
    const float* Wi = (const float*)d_in[1];
    const float* Wh = (const float*)d_in[2];
    const float* bh = (const float*)d_in[3];
    const float* Wo = (const float*)d_in[4];
    const float* bo = (const float*)d_in[5];
    float* out = (float*)d_out;

    lstm_mfma4w<<<dim3(Bsz / 16), dim3(256), 0, stream>>>(x, Wi, Wh, bh, Wo, bo, out);
}

// Round 7
// 146.235 us; speedup vs baseline: 1.9200x; 1.1336x over previous
//
#include <hip/hip_runtime.h>

// Autoregressive LSTM log-prob via MFMA, 8-wave split-cell design.
// B=4096, L=256, H=32, D=2. 256 WGs x 512 threads (8 waves), 16 batches/WG.
// Orientation: gates^T = Wh^T @ h^T (A = weights, B = h, batch = lane&15).
// Wave w (rot=w&3, half=w>>2) computes only the 4 gate-tiles of its unit
// half and cell-updates ONE unit per lane: u = 4*oct + rot + 16*half.
// A-fragments row-rotated by rot so that unit's gates land in acc reg 0.
// Bias (bh + Wi[spin]) rides in the MFMA C operand (reg 0 of a persistent
// zero quad). h exchange: double-buffered LDS rows (stride 72 B), identity
// slot map (unit u at byte 2u), 2 x ds_read_b64 per lane, one barrier/step.
// 2 waves/SIMD for stall overlap (R4->R6 scaling evidence). Logits buffered
// raw in LDS; ELU + log-softmax + time reduction post-loop.

typedef __attribute__((ext_vector_type(8))) short bf16x8;
typedef __attribute__((ext_vector_type(4))) float f32x4;

#define LOG2E 1.4426950408889634f
#define LN2   0.6931471805599453f

__device__ __forceinline__ float fexp2(float x) { return __builtin_amdgcn_exp2f(x); }
__device__ __forceinline__ float flog2(float x) { return __builtin_amdgcn_logf(x); }
__device__ __forceinline__ float frcp(float x)  { return __builtin_amdgcn_rcpf(x); }

__device__ __forceinline__ float fsig(float x)   { return frcp(1.f + fexp2(-LOG2E * x)); }
__device__ __forceinline__ float ftanh_(float x) { return 1.f - 2.f * frcp(fexp2(2.f * LOG2E * x) + 1.f); }
__device__ __forceinline__ float felu(float x)   { return x > 0.f ? x : fexp2(LOG2E * x) - 1.f; }

__device__ __forceinline__ unsigned short f2bf(float f) {   // RNE f32->bf16
    unsigned u = __builtin_bit_cast(unsigned, f);
    u = (u + 0x7FFFu + ((u >> 16) & 1u)) >> 16;
    return (unsigned short)u;
}

constexpr int Bsz = 4096;

__global__ __launch_bounds__(512, 2) void lstm_mfma8w(
    const int*   __restrict__ x,    // [B, 256]
    const float* __restrict__ Wi,   // [2, 128]
    const float* __restrict__ Wh,   // [32, 128]
    const float* __restrict__ bh,   // [128]
    const float* __restrict__ Wo,   // [32, 2]
    const float* __restrict__ bo,   // [2]
    float*       __restrict__ out)  // [B]
{
    const int tid  = threadIdx.x;
    const int w    = tid >> 6;      // wave 0..7
    const int lane = tid & 63;
    const int m    = lane & 15;     // batch column
    const int oct  = lane >> 4;
    const int rot  = w & 3;         // gate-row rotation
    const int half = w >> 2;        // unit half (0: units 0-15, 1: 16-31)
    const int b0   = blockIdx.x * 16;

    __shared__ char   spinT[16][260];     // [batch][t] bytes, padded row
    __shared__ float2 Sbuf[256][16];      // raw logits (S0,S1) per (t,batch)
    __shared__ short  hbuf[2][16][36];    // h dbuf, row stride 72 B, slot u = unit u
    __shared__ float  red[8][16];

    // ---- stage spins: 512 threads x 8 ints ----
    {
        const int bl = tid >> 5;
        const int c8 = (tid & 31) * 8;
        const int4* src = reinterpret_cast<const int4*>(x + (b0 + bl) * 256 + c8);
        const int4 v0 = src[0], v1 = src[1];
        const int p0 = (v0.x & 1) | ((v0.y & 1) << 8) | ((v0.z & 1) << 16) | ((v0.w & 1) << 24);
        const int p1 = (v1.x & 1) | ((v1.y & 1) << 8) | ((v1.z & 1) << 16) | ((v1.w & 1) << 24);
        *reinterpret_cast<int*>(&spinT[bl][c8])     = p0;
        *reinterpret_cast<int*>(&spinT[bl][c8 + 4]) = p1;
    }

    // ---- weight A-frags: 4 tiles (gate q, unit-half `half`), rows rotated
    // by rot. A[row=lane&15][k=oct*8+j] = gs * Wh[unit oct*8+j][gate-col].
    bf16x8 wfrag[4];
#pragma unroll
    for (int q = 0; q < 4; ++q) {
        const float gs = (q == 2) ? 2.f * LOG2E : -LOG2E;
        const int colg = 32 * q + 16 * half + ((m + rot) & 15);
#pragma unroll
        for (int j = 0; j < 8; ++j)
            wfrag[q][j] = (short)f2bf(gs * Wh[(oct * 8 + j) * 128 + colg]);
    }
    bf16x8 wofragA;   // head: Wo^T padded to 16 rows (wave 0, rot=0)
#pragma unroll
    for (int j = 0; j < 8; ++j)
        wofragA[j] = (m < 2) ? (short)f2bf(Wo[(oct * 8 + j) * 2 + m]) : (short)0;

    // ---- this lane's cell + its scaled biases ----
    const int ucell = 4 * oct + rot + 16 * half;
    float bv0[4], bvd[4];
#pragma unroll
    for (int q = 0; q < 4; ++q) {
        const float gs = (q == 2) ? 2.f * LOG2E : -LOG2E;
        const int colg0 = 32 * q + ucell;
        bv0[q] = gs * (bh[colg0] + Wi[colg0]);
        bvd[q] = gs * (Wi[128 + colg0] - Wi[colg0]);
    }
    const float bo0 = bo[0], bo1 = bo[1];

    // ---- peel t=0: input zeros, h=c=0 -> gates = bh ----
    float c;
    {
        c = fsig(bh[ucell]) * ftanh_(bh[64 + ucell]);
        const float h0 = fsig(bh[96 + ucell]) * ftanh_(c);
        hbuf[0][m][ucell] = (short)f2bf(h0);
    }
    __syncthreads();

    const f32x4 zero4 = { 0.f, 0.f, 0.f, 0.f };
    f32x4 ccq[4] = { zero4, zero4, zero4, zero4 };   // persistent C quads
    float spf = (float)spinT[m][0];                  // x[0], consumed at t=1

    for (int t = 1; t < 256; ++t) {
        // B-frag: h_{t-1}, this lane's 8 slots (units oct*8..oct*8+7)
        const short4* hp =
            reinterpret_cast<const short4*>(&hbuf[(t + 1) & 1][m][8 * oct]);
        const short4 ra = hp[0], rb = hp[1];
        union { bf16x8 v; short4 s[2]; } hu;
        hu.s[0] = ra; hu.s[1] = rb;
        const bf16x8 hfrag = hu.v;

        // bias into C reg 0 (spin_{t-1} selects Wi row)
#pragma unroll
        for (int q = 0; q < 4; ++q) ccq[q][0] = fmaf(spf, bvd[q], bv0[q]);

        f32x4 acc[4];
#pragma unroll
        for (int q = 0; q < 4; ++q)
            acc[q] = __builtin_amdgcn_mfma_f32_16x16x32_bf16(wfrag[q], hfrag, ccq[q], 0, 0, 0);

        if (w == 0) {   // head: logits of step t-1 (wave-uniform branch)
            const f32x4 hacc =
                __builtin_amdgcn_mfma_f32_16x16x32_bf16(wofragA, hfrag, zero4, 0, 0, 0);
            if (oct == 0) Sbuf[t - 1][m] = make_float2(hacc[0], hacc[1]);
        }

        const float spn = (float)spinT[m][t];   // prefetch next spin

        // cell update (gates in acc[q][0], scales pre-folded:
        // e_i=e^{-i}, e_f=e^{-f}, e_g=e^{2g}, e_o=e^{-o})
        {
            const float ei = fexp2(acc[0][0]), ef = fexp2(acc[1][0]);
            const float eg = fexp2(acc[2][0]), eo = fexp2(acc[3][0]);
            const float gf = frcp(1.f + ef);
            const float igt = (eg - 1.f) * frcp((1.f + ei) * (1.f + eg));
            c = fmaf(gf, c, igt);
            const float ec = fexp2(2.f * LOG2E * c);
            const float h  = (ec - 1.f) * frcp((1.f + eo) * (1.f + ec));
            hbuf[t & 1][m][ucell] = (short)f2bf(h);
        }

        spf = spn;
        __syncthreads();   // h_t visible to all waves
    }

    // ---- tail: logits of step 255 (h_255 in hbuf[1]) ----
    if (w == 0) {
        const short4* hp = reinterpret_cast<const short4*>(&hbuf[1][m][8 * oct]);
        const short4 ra = hp[0], rb = hp[1];
        union { bf16x8 v; short4 s[2]; } hu;
        hu.s[0] = ra; hu.s[1] = rb;
        const f32x4 hacc =
            __builtin_amdgcn_mfma_f32_16x16x32_bf16(wofragA, hu.v, zero4, 0, 0, 0);
        if (oct == 0) Sbuf[255][m] = make_float2(hacc[0], hacc[1]);
    }
    __syncthreads();

    // ---- post phase: ELU + log-softmax + sum over t, 32 time-chunks ----
    float lp = 0.f;
    {
        const int t0 = (w * 4 + oct) * 8;
#pragma unroll
        for (int i = 0; i < 8; ++i) {
            const int t = t0 + i;
            const float2 sv = Sbuf[t][m];
            const int sp = spinT[m][t];
            const float o0 = felu(sv.x + bo0);
            const float o1 = felu(sv.y + bo1);
            const float mx = fmaxf(o0, o1), mn = fminf(o0, o1);
            const float lse = mx + LN2 * flog2(1.f + fexp2(LOG2E * (mn - mx)));
            lp += (sp ? o1 : o0) - lse;
        }
    }
    lp += __shfl_xor(lp, 16, 64);   // reduce over oct
    lp += __shfl_xor(lp, 32, 64);
    if (lane < 16) red[w][lane] = lp;
    __syncthreads();
    if (tid < 16) {
        float s = 0.f;
#pragma unroll
        for (int ww = 0; ww < 8; ++ww) s += red[ww][tid];
        out[b0 + tid] = 0.5f * s;
    }
}

extern "C" void kernel_launch(void* const* d_in, const int* in_sizes, int n_in,
                              void* d_out, int out_size, void* d_ws, size_t ws_size,
                              hipStream_t stream) {
    const int*   x  = (const int*)d_in[0];
    const float* Wi = (const float*)d_in[1];
    const float* Wh = (const float*)d_in[2];
    const float* bh = (const float*)d_in[3];
    const float* Wo = (const float*)d_in[4];
    const float* bo = (const float*)d_in[5];
    float* out = (float*)d_out;

    lstm_mfma8w<<<dim3(Bsz / 16), dim3(512), 0, stream>>>(x, Wi, Wh, bh, Wo, bo, out);
}